// Round 1
// baseline (666.317 us; speedup 1.0000x reference)
//
#include <hip/hip_runtime.h>
#include <cstdint>
#include <cstddef>

#define NF 10240

typedef _Float16 half8_t __attribute__((ext_vector_type(8)));
typedef float floatx4 __attribute__((ext_vector_type(4)));

// ---------------------------------------------------------------------------
// k1: deg[j] = column sums of A' (supports with self-loop fix on diagonal).
// Fix only changes deg when supports[i,i]==0 (add 1).  Grid: (10 col-tiles of
// 1024) x (80 row-chunks of 128).  Each thread owns 4 consecutive cols.
// ---------------------------------------------------------------------------
__global__ __launch_bounds__(256) void k_deg(const float* __restrict__ sup,
                                             float* __restrict__ deg) {
  const int tid = threadIdx.x;
  const int c = blockIdx.x * 1024 + tid * 4;
  const int r0 = blockIdx.y * 128;
  const float* p = sup + (size_t)r0 * NF + c;
  float a[4] = {0.f, 0.f, 0.f, 0.f};
  for (int k = 0; k < 128; ++k) {
    const float4 v = *(const float4*)p;
    p += NF;
    a[0] += v.x; a[1] += v.y; a[2] += v.z; a[3] += v.w;
  }
#pragma unroll
  for (int e = 0; e < 4; ++e) {
    const int i = c + e;
    if (i >= r0 && i < r0 + 128) {           // this block owns the diag row
      if (sup[(size_t)i * NF + i] == 0.f) a[e] += 1.f;
    }
  }
#pragma unroll
  for (int e = 0; e < 4; ++e) atomicAdd(&deg[c + e], a[e]);
}

// ---------------------------------------------------------------------------
// k2: h[b,i,:] = xf[b,i,:] @ W_gcn (no bias), g = dinv[i]*h, packed fp16 into
// MFMA B-fragment layout: halfword index ((i>>3)*64 + (b*16+o))*8 + (i&7).
// Also writes dinv[] for k4.  40960 threads (one per (b,i)).
// ---------------------------------------------------------------------------
__global__ __launch_bounds__(256) void k_g(const float* __restrict__ x,
                                           const float* __restrict__ Wg,
                                           const float* __restrict__ deg,
                                           float* __restrict__ dinv,
                                           _Float16* __restrict__ gp) {
  __shared__ float w[256];
  w[threadIdx.x] = Wg[threadIdx.x];          // 16x16 = exactly 256
  __syncthreads();
  const int t = blockIdx.x * 256 + threadIdx.x;   // b*NF + i
  const int b = t / NF;
  const int i = t % NF;
  float xv[16];
  const float* xp = x + (size_t)t * 16;
#pragma unroll
  for (int d = 0; d < 16; ++d) xv[d] = xp[d];
  const float dg = deg[i];
  const float di = dg > 0.f ? rsqrtf(dg) : 0.f;
  if (b == 0) dinv[i] = di;
  const int base = ((i >> 3) * 64 + b * 16) * 8 + (i & 7);
#pragma unroll
  for (int o = 0; o < 16; ++o) {
    float h = 0.f;
#pragma unroll
    for (int d = 0; d < 16; ++d) h += xv[d] * w[d * 16 + o];
    gp[base + o * 8] = (_Float16)(h * di);
  }
}

// ---------------------------------------------------------------------------
// k3: C_p[p][j][bo] = sum_{i in K-split p} A'[i,j] * g[i,bo]  via
// mfma_f32_16x16x32_f16.  M=j (64/block), N=bo (16/wave), K=i.
// supports rows staged coalesced -> LDS transposed (pad 65: conflict-free
// writes, 2-way reads = free), fp32->fp16 convert at fragment assembly.
// A-frag: lane holds A[m=lane&15][k=quad*8+j] (k-contiguous in LDS-T row).
// C/D: col=lane&15 (bo), row=quad*4+reg (j_local).   [layouts per m89/m91]
// ---------------------------------------------------------------------------
__global__ __launch_bounds__(256) void k_gemm(const float* __restrict__ sup,
                                              const half8_t* __restrict__ gp8,
                                              float* __restrict__ Cp,
                                              int kRange, int nchunk) {
  __shared__ float ldsA[64 * 65];
  const int tid = threadIdx.x;
  const int lane = tid & 63;
  const int w = tid >> 6;       // wave id = N-slice (bo/16)
  const int x = lane & 15;
  const int q = lane >> 4;
  const int jbase = blockIdx.x * 64;
  const int kbase0 = blockIdx.y * kRange;

  floatx4 acc[4] = {};

  const int stage_r = tid >> 4;        // 0..15
  const int stage_c = (tid & 15) * 4;  // 0..60

  for (int ch = 0; ch < nchunk; ++ch) {
    const int kbase = kbase0 + ch * 64;
    __syncthreads();                   // protect LDS from prev-chunk readers
#pragma unroll
    for (int pass = 0; pass < 4; ++pass) {
      const int r = stage_r + pass * 16;
      const int gi = kbase + r;
      float4 v = *(const float4*)(sup + (size_t)gi * NF + jbase + stage_c);
      const int gj = jbase + stage_c;
      if (gi == gj     && v.x == 0.f) v.x = 1.f;   // self-loop fix
      if (gi == gj + 1 && v.y == 0.f) v.y = 1.f;
      if (gi == gj + 2 && v.z == 0.f) v.z = 1.f;
      if (gi == gj + 3 && v.w == 0.f) v.w = 1.f;
      float* d = &ldsA[stage_c * 65 + r];          // transposed: [m][k]
      d[0] = v.x; d[65] = v.y; d[130] = v.z; d[195] = v.w;
    }
    __syncthreads();
    const int k8base = kbase >> 3;
#pragma unroll
    for (int s = 0; s < 2; ++s) {
      // B fragment: g[k=quad*8+jj][n=w*16+x], k8 = k8base + s*4 + q
      const half8_t bfrag = gp8[(k8base + s * 4 + q) * 64 + w * 16 + x];
#pragma unroll
      for (int ms = 0; ms < 4; ++ms) {
        const float* ap = &ldsA[(ms * 16 + x) * 65 + s * 32 + q * 8];
        half8_t afrag;
#pragma unroll
        for (int jj = 0; jj < 8; ++jj) afrag[jj] = (_Float16)ap[jj];
        acc[ms] = __builtin_amdgcn_mfma_f32_16x16x32_f16(afrag, bfrag,
                                                         acc[ms], 0, 0, 0);
      }
    }
  }

  const size_t pbase = (size_t)blockIdx.y * NF;
#pragma unroll
  for (int ms = 0; ms < 4; ++ms) {
#pragma unroll
    for (int r = 0; r < 4; ++r) {
      const int j = jbase + ms * 16 + q * 4 + r;
      Cp[(pbase + j) * 64 + w * 16 + x] = acc[ms][r];
    }
  }
}

// ---------------------------------------------------------------------------
// k4: per n: sum K-split partials, relu(dinv[j]*C + b_gcn), then
// (160) @ W_out(160,16) + b_out.  One block per n.
// ---------------------------------------------------------------------------
__global__ __launch_bounds__(256) void k_out(const float* __restrict__ Cp,
                                             const float* __restrict__ dinv,
                                             const float* __restrict__ bgcn,
                                             const float* __restrict__ Wout,
                                             const float* __restrict__ bout,
                                             float* __restrict__ out, int S) {
  __shared__ float wl[2560];
  __shared__ float tmp[640];
  const int n = blockIdx.x;
  const int t = threadIdx.x;
  for (int idx = t; idx < 2560; idx += 256) wl[idx] = Wout[idx];
  if (t < 160) {
    const int f = t >> 4, o = t & 15;
    const int j = n * 10 + f;
    const float di = dinv[j];
    const float bg = bgcn[o];
    for (int b = 0; b < 4; ++b) {
      float s = 0.f;
      for (int p = 0; p < S; ++p)
        s += Cp[((size_t)(p * NF + j)) * 64 + b * 16 + o];
      const float v = di * s + bg;
      tmp[b * 160 + t] = v > 0.f ? v : 0.f;
    }
  }
  __syncthreads();
  if (t < 64) {
    const int b = t >> 4, oc = t & 15;
    float acc = bout[oc];
    for (int k = 0; k < 160; ++k) acc += tmp[b * 160 + k] * wl[k * 16 + oc];
    out[((size_t)(b * 1024 + n)) * 16 + oc] = acc;
  }
}

// ---------------------------------------------------------------------------
extern "C" void kernel_launch(void* const* d_in, const int* in_sizes, int n_in,
                              void* d_out, int out_size, void* d_ws,
                              size_t ws_size, hipStream_t stream) {
  const float* x   = (const float*)d_in[0];   // (4,1024,10,16)
  // d_in[1..2]: factor/grid embeddings — dead code in reference
  const float* sup = (const float*)d_in[3];   // (10240,10240)
  // d_in[4..5]: ln_gamma/ln_beta — dead code
  const float* Wg  = (const float*)d_in[6];   // (16,16)
  const float* bg  = (const float*)d_in[7];   // (16,)
  const float* Wo  = (const float*)d_in[8];   // (160,16)
  const float* bo  = (const float*)d_in[9];   // (16,)
  float* out = (float*)d_out;

  char* ws = (char*)d_ws;
  float*     deg  = (float*)ws;                          // 40 KB
  float*     dinv = (float*)(ws + 40960);                // 40 KB
  _Float16*  gp   = (_Float16*)(ws + 81920);             // 1.31 MB
  float*     Cp   = (float*)(ws + 81920 + 1310720);      // S*10240*64*4

  // K-split factor: prefer 8 (better occupancy) if workspace allows.
  const size_t head = 81920 + 1310720;
  const int S = (ws_size >= head + (size_t)8 * NF * 64 * 4) ? 8 : 4;
  const int kRange = NF / S;
  const int nchunk = kRange / 64;

  hipMemsetAsync(deg, 0, NF * sizeof(float), stream);
  k_deg<<<dim3(10, 80), 256, 0, stream>>>(sup, deg);
  k_g<<<160, 256, 0, stream>>>(x, Wg, deg, dinv, gp);
  k_gemm<<<dim3(160, S), 256, 0, stream>>>(sup, (const half8_t*)gp, Cp,
                                           kRange, nchunk);
  k_out<<<1024, 256, 0, stream>>>(Cp, dinv, bg, Wo, bo, out, S);
}